// Round 2
// baseline (682.755 us; speedup 1.0000x reference)
//
#include <hip/hip_runtime.h>

// LoRA attention: B=4, S=2048, E=1024, R=16, fp32 in/out.
// bf16 MFMA (16x16x32) for all GEMMs, fp32 accumulate.
// R2 changes vs R1:
//  - Fragment-major LDS tile layout (swizzled global_load_lds lane->chunk
//    mapping) so fragment ds_read_b128 is lane-contiguous => 0 bank conflicts
//    (was 8-way, 4.19M conflict cycles on the scores GEMM).
//  - Kernel fusion: q/k/v cvt + LoRA-T in one kernel (saves a 100MB fp32
//    re-read), 4 weight cvts batched, 3 B-mat cvts batched, Q+K proj GEMMs
//    batched via grid.z. 20 launches -> 9.

#define S_LEN 2048
#define E_DIM 1024

typedef __attribute__((ext_vector_type(8))) short short8;
typedef __attribute__((ext_vector_type(4))) float floatx4;

__device__ __forceinline__ unsigned short f2bf(float f) {
  union { float f; unsigned int u; } x; x.f = f;
  return (unsigned short)((x.u + 0x7fffu + ((x.u >> 16) & 1u)) >> 16);  // RNE
}
__device__ __forceinline__ float bf2f(unsigned short h) {
  union { unsigned int u; float f; } x; x.u = ((unsigned int)h) << 16;
  return x.f;
}

__device__ __forceinline__ void gld_lds16(const unsigned short* g, unsigned short* l) {
  __builtin_amdgcn_global_load_lds(
      (const __attribute__((address_space(1))) unsigned int*)(const void*)g,
      (__attribute__((address_space(3))) unsigned int*)(void*)l,
      16, 0, 0);
}

// C[m][n] = scale * (sum_k A[m][k]*B[n][k]  (+ LoRA: sum_r LA[m][r]*LB[n][r]))
// LDS tile layout is FRAGMENT-MAJOR: 16B chunk (row,kc) lives at chunk index
//   (row>>4)*64 + kc*16 + (row&15)
// so a wave's fragment read is ds_read_b128 at base + lane*16 (conflict-free),
// and global_load_lds staging (chunk = wave*64+lane) sources
//   row = wave*16 + (lane&15), kc = (lane>>4)&3.
template<bool LORA, bool OUTF32>
__global__ __launch_bounds__(256) void gemm_bt(
    const unsigned short* __restrict__ A, const unsigned short* __restrict__ B,
    void* __restrict__ Cv,
    const unsigned short* __restrict__ LA, const unsigned short* __restrict__ LB,
    long lda, long ldb, long ldc, int K, float scale,
    long batA, long batB, long batC, long batLA, long batLB) {
  __shared__ alignas(16) unsigned short As[4096];  // 128 rows x 32 bf16
  __shared__ alignas(16) unsigned short Bs[4096];

  const int tid  = threadIdx.x;
  const int wave = tid >> 6, lane = tid & 63;
  const int quad = lane >> 4, l16 = lane & 15;
  const int wr = wave >> 1, wc = wave & 1;  // 2x2 waves, each 64x64
  const long m0 = (long)blockIdx.y * 128;
  const long n0 = (long)blockIdx.x * 128;
  A += (long)blockIdx.z * batA;
  B += (long)blockIdx.z * batB;

  floatx4 acc[4][4];
#pragma unroll
  for (int i = 0; i < 4; ++i)
#pragma unroll
    for (int j = 0; j < 4; ++j) acc[i][j] = (floatx4){0.f, 0.f, 0.f, 0.f};

  // swizzled staging source: chunk = wave*64+lane -> row wave*16+(lane&15),
  // k-offset ((lane>>4)&3)*8 elems
  const long srow  = (long)((tid >> 6) * 16 + (tid & 15));
  const int  skoff = ((tid >> 4) & 3) * 8;
  const unsigned short* a_base = A + (m0 + srow) * lda + skoff;
  const unsigned short* b_base = B + (n0 + srow) * ldb + skoff;
  unsigned short* as0 = &As[wave * 512];
  unsigned short* as1 = &As[2048 + wave * 512];
  unsigned short* bs0 = &Bs[wave * 512];
  unsigned short* bs1 = &Bs[2048 + wave * 512];

  for (int k0 = 0; k0 < K; k0 += 32) {
    gld_lds16(a_base + k0, as0);
    gld_lds16(a_base + 64 * lda + k0, as1);
    gld_lds16(b_base + k0, bs0);
    gld_lds16(b_base + 64 * ldb + k0, bs1);
    __syncthreads();
    short8 afrag[4], bfrag[4];
#pragma unroll
    for (int i = 0; i < 4; ++i)
      afrag[i] = *(const short8*)&As[((wr * 4 + i) * 64 + lane) * 8];
#pragma unroll
    for (int j = 0; j < 4; ++j)
      bfrag[j] = *(const short8*)&Bs[((wc * 4 + j) * 64 + lane) * 8];
#pragma unroll
    for (int i = 0; i < 4; ++i)
#pragma unroll
      for (int j = 0; j < 4; ++j)
        acc[i][j] = __builtin_amdgcn_mfma_f32_16x16x32_bf16(afrag[i], bfrag[j], acc[i][j], 0, 0, 0);
    __syncthreads();
  }

  if constexpr (LORA) {
    const unsigned short* LAz = LA + (long)blockIdx.z * batLA;
    const unsigned short* LBz = LB + (long)blockIdx.z * batLB;
    // one extra K-step: row r gets LA[m0+r][0..16) zero-padded to 32.
    // fragment-major chunks: (r>>4)*64 + kc*16 + (r&15), kc 0..3 (2,3 zero)
    const int r = tid >> 1, h = tid & 1;
    const int cbase = (r >> 4) * 64 + (r & 15) + h * 32;
    uint4* a0 = (uint4*)&As[cbase * 8];
    uint4* a1 = (uint4*)&As[(cbase + 16) * 8];
    uint4* b0 = (uint4*)&Bs[cbase * 8];
    uint4* b1 = (uint4*)&Bs[(cbase + 16) * 8];
    if (h == 0) {
      const uint4* sa = (const uint4*)(LAz + (m0 + r) * 16);
      a0[0] = sa[0]; a1[0] = sa[1];
      const uint4* sb = (const uint4*)(LBz + (n0 + r) * 16);
      b0[0] = sb[0]; b1[0] = sb[1];
    } else {
      uint4 z; z.x = z.y = z.z = z.w = 0u;
      a0[0] = z; a1[0] = z; b0[0] = z; b1[0] = z;
    }
    __syncthreads();
    short8 afrag[4], bfrag[4];
#pragma unroll
    for (int i = 0; i < 4; ++i)
      afrag[i] = *(const short8*)&As[((wr * 4 + i) * 64 + lane) * 8];
#pragma unroll
    for (int j = 0; j < 4; ++j)
      bfrag[j] = *(const short8*)&Bs[((wc * 4 + j) * 64 + lane) * 8];
#pragma unroll
    for (int i = 0; i < 4; ++i)
#pragma unroll
      for (int j = 0; j < 4; ++j)
        acc[i][j] = __builtin_amdgcn_mfma_f32_16x16x32_bf16(afrag[i], bfrag[j], acc[i][j], 0, 0, 0);
  }

  // epilogue: C/D layout col=lane&15, row=quad*4+rr
#pragma unroll
  for (int i = 0; i < 4; ++i) {
    const long row = m0 + wr * 64 + i * 16 + quad * 4;
#pragma unroll
    for (int j = 0; j < 4; ++j) {
      const long col = n0 + wc * 64 + j * 16 + l16;
#pragma unroll
      for (int rr = 0; rr < 4; ++rr) {
        float val = acc[i][j][rr] * scale;
        if constexpr (OUTF32)
          ((float*)Cv)[(long)blockIdx.z * batC + (row + rr) * ldc + col] = val;
        else
          ((unsigned short*)Cv)[(long)blockIdx.z * batC + (row + rr) * ldc + col] = f2bf(val);
      }
    }
  }
}

__device__ __forceinline__ uint4 pack8(const float* x) {
  float4 a = *(const float4*)x;
  float4 b = *(const float4*)(x + 4);
  uint4 o;
  o.x = (unsigned int)f2bf(a.x) | ((unsigned int)f2bf(a.y) << 16);
  o.y = (unsigned int)f2bf(a.z) | ((unsigned int)f2bf(a.w) << 16);
  o.z = (unsigned int)f2bf(b.x) | ((unsigned int)f2bf(b.y) << 16);
  o.w = (unsigned int)f2bf(b.z) | ((unsigned int)f2bf(b.w) << 16);
  return o;
}

// fused: fp32->bf16 convert of q/k/v (16 rows of 1024 per block) + LoRA
// T[m][r] = sum_k X[m][k]*Am[r][k]. grid (512, 3).
__global__ __launch_bounds__(256) void prep_qkv(
    const float* __restrict__ q, const float* __restrict__ k, const float* __restrict__ v,
    const float* __restrict__ QA, const float* __restrict__ KA, const float* __restrict__ VA,
    unsigned short* __restrict__ qb, unsigned short* __restrict__ kb, unsigned short* __restrict__ vb,
    unsigned short* __restrict__ Tq, unsigned short* __restrict__ Tk, unsigned short* __restrict__ Tv) {
  const float* X; const float* Am; unsigned short* Y; unsigned short* T;
  if (blockIdx.y == 0)      { X = q; Am = QA; Y = qb; T = Tq; }
  else if (blockIdx.y == 1) { X = k; Am = KA; Y = kb; T = Tk; }
  else                      { X = v; Am = VA; Y = vb; T = Tv; }
  const int tid = threadIdx.x;
  const long blk = (long)blockIdx.x * 16384;
  // phase 1: convert (coalesced: 256 threads x 8 floats per iter)
#pragma unroll
  for (int it = 0; it < 8; ++it) {
    const long idx = blk + it * 2048 + tid * 8;
    *(uint4*)(Y + idx) = pack8(X + idx);
  }
  // phase 2: T (X rows are L1/L2-hot from phase 1; Am is L2-resident)
  const long m = (long)blockIdx.x * 16 + (tid >> 4);
  const int r = tid & 15;
  const float* xr = X + m * 1024;
  const float* ar = Am + (long)r * 1024;
  float s = 0.f;
#pragma unroll 4
  for (int kk = 0; kk < 1024; kk += 4) {
    float4 xv = *(const float4*)(xr + kk);
    float4 av = *(const float4*)(ar + kk);
    s += xv.x * av.x + xv.y * av.y + xv.z * av.z + xv.w * av.w;
  }
  T[m * 16 + r] = f2bf(s);
}

// 4 weight matrices (1048576 elems each), grid (512, 4)
__global__ __launch_bounds__(256) void cvt4(
    const float* __restrict__ x0, const float* __restrict__ x1,
    const float* __restrict__ x2, const float* __restrict__ x3,
    unsigned short* __restrict__ y0, unsigned short* __restrict__ y1,
    unsigned short* __restrict__ y2, unsigned short* __restrict__ y3) {
  const float* x; unsigned short* y;
  switch (blockIdx.y) {
    case 0: x = x0; y = y0; break;
    case 1: x = x1; y = y1; break;
    case 2: x = x2; y = y2; break;
    default: x = x3; y = y3; break;
  }
  const long i = ((long)blockIdx.x * 256 + threadIdx.x) * 8;
  *(uint4*)(y + i) = pack8(x + i);
}

// 3 LoRA-B matrices (16384 elems each), grid (8, 3)
__global__ __launch_bounds__(256) void cvt3(
    const float* __restrict__ x0, const float* __restrict__ x1, const float* __restrict__ x2,
    unsigned short* __restrict__ y0, unsigned short* __restrict__ y1, unsigned short* __restrict__ y2) {
  const float* x; unsigned short* y;
  switch (blockIdx.y) {
    case 0: x = x0; y = y0; break;
    case 1: x = x1; y = y1; break;
    default: x = x2; y = y2; break;
  }
  const long i = ((long)blockIdx.x * 256 + threadIdx.x) * 8;
  *(uint4*)(y + i) = pack8(x + i);
}

// in-place row softmax over 2048 bf16 scores; one block per row
__global__ __launch_bounds__(256) void softmax_kernel(unsigned short* __restrict__ S) {
  const long base = (long)blockIdx.x * 2048;
  const int tid = threadIdx.x;
  const int lane = tid & 63, wave = tid >> 6;
  __shared__ float redm[4], reds[4];
  uint4 raw = *(const uint4*)(S + base + tid * 8);
  unsigned int w[4] = {raw.x, raw.y, raw.z, raw.w};
  float v[8];
#pragma unroll
  for (int i = 0; i < 4; ++i) {
    v[2 * i]     = bf2f((unsigned short)(w[i] & 0xffffu));
    v[2 * i + 1] = bf2f((unsigned short)(w[i] >> 16));
  }
  float m = v[0];
#pragma unroll
  for (int i = 1; i < 8; ++i) m = fmaxf(m, v[i]);
  for (int off = 32; off >= 1; off >>= 1) m = fmaxf(m, __shfl_xor(m, off, 64));
  if (lane == 0) redm[wave] = m;
  __syncthreads();
  m = fmaxf(fmaxf(redm[0], redm[1]), fmaxf(redm[2], redm[3]));
  float e[8], s = 0.f;
#pragma unroll
  for (int i = 0; i < 8; ++i) { e[i] = __expf(v[i] - m); s += e[i]; }
  for (int off = 32; off >= 1; off >>= 1) s += __shfl_xor(s, off, 64);
  if (lane == 0) reds[wave] = s;
  __syncthreads();
  s = reds[0] + reds[1] + reds[2] + reds[3];
  const float inv = 1.0f / s;
  uint4 o;
  o.x = (unsigned int)f2bf(e[0] * inv) | ((unsigned int)f2bf(e[1] * inv) << 16);
  o.y = (unsigned int)f2bf(e[2] * inv) | ((unsigned int)f2bf(e[3] * inv) << 16);
  o.z = (unsigned int)f2bf(e[4] * inv) | ((unsigned int)f2bf(e[5] * inv) << 16);
  o.w = (unsigned int)f2bf(e[6] * inv) | ((unsigned int)f2bf(e[7] * inv) << 16);
  *(uint4*)(S + base + tid * 8) = o;
}

extern "C" void kernel_launch(void* const* d_in, const int* in_sizes, int n_in,
                              void* d_out, int out_size, void* d_ws, size_t ws_size,
                              hipStream_t stream) {
  const float* q  = (const float*)d_in[0];
  const float* k  = (const float*)d_in[1];
  const float* v  = (const float*)d_in[2];
  const float* Wq = (const float*)d_in[3];
  const float* Wk = (const float*)d_in[4];
  const float* Wv = (const float*)d_in[5];
  const float* QA = (const float*)d_in[6];
  const float* QB = (const float*)d_in[7];
  const float* KA = (const float*)d_in[8];
  const float* KB = (const float*)d_in[9];
  const float* VA = (const float*)d_in[10];
  const float* VB = (const float*)d_in[11];
  const float* Wo = (const float*)d_in[12];

  unsigned short* W = (unsigned short*)d_ws;
  const long SEe = (long)8192 * 1024;  // 8388608
  unsigned short* qb  = W;             // dead after Q-proj -> scores low half
  unsigned short* kb  = W + SEe;
  unsigned short* vb  = W + 2 * SEe;   // dead after V-proj -> attn buffer
  unsigned short* Qp  = W + 3 * SEe;
  unsigned short* Kp  = W + 4 * SEe;
  unsigned short* VT  = W + 5 * SEe;   // [1024][8192] = V^T
  unsigned short* wqb = W + 6 * SEe;
  unsigned short* wkb = wqb + 1048576;
  unsigned short* wvb = wkb + 1048576;
  unsigned short* wob = wvb + 1048576;
  unsigned short* Bqb = wob + 1048576;
  unsigned short* Bkb = Bqb + 16384;
  unsigned short* Bvb = Bkb + 16384;
  unsigned short* Tq  = Bvb + 16384;   // [8192][16]
  unsigned short* Tk  = Tq + 131072;
  unsigned short* Tv  = Tk + 131072;
  unsigned short* scores = W;          // [4][2048][2048] bf16, aliases qb+kb
  unsigned short* attn   = vb;         // [8192][1024] bf16, aliases vb

  dim3 blk(256, 1, 1);
  prep_qkv<<<dim3(512, 3, 1), blk, 0, stream>>>(q, k, v, QA, KA, VA, qb, kb, vb, Tq, Tk, Tv);
  cvt4<<<dim3(512, 4, 1), blk, 0, stream>>>(Wq, Wk, Wv, Wo, wqb, wkb, wvb, wob);
  cvt3<<<dim3(8, 3, 1), blk, 0, stream>>>(QB, KB, VB, Bqb, Bkb, Bvb);

  // Q = qb@Wq^T + Tq@Bq^T ; K likewise (z batches both; M=8192,N=1024,K=1024)
  gemm_bt<true, false><<<dim3(8, 64, 2), blk, 0, stream>>>(
      qb, wqb, Qp, Tq, Bqb, 1024, 1024, 1024, 1024, 1.0f,
      SEe, 1048576, SEe, 131072, 16384);
  // VT = Wv@vb^T + Bv@Tv^T  (M=1024,N=8192, C row-stride 8192)
  gemm_bt<true, false><<<dim3(64, 8, 1), blk, 0, stream>>>(
      wvb, vb, VT, Bvb, Tv, 1024, 1024, 8192, 1024, 1.0f, 0, 0, 0, 0, 0);
  // scores = Qp@Kp^T / 32   (batched, M=N=2048,K=1024)
  gemm_bt<false, false><<<dim3(16, 16, 4), blk, 0, stream>>>(
      Qp, Kp, scores, nullptr, nullptr, 1024, 1024, 2048, 1024, 0.03125f,
      (long)S_LEN * E_DIM, (long)S_LEN * E_DIM, (long)S_LEN * S_LEN, 0, 0);
  softmax_kernel<<<8192, blk, 0, stream>>>(scores);
  // attn_out = P@V = P@(VT)^T  (batched, M=2048,N=1024,K=2048)
  gemm_bt<false, false><<<dim3(8, 16, 4), blk, 0, stream>>>(
      scores, VT, attn, nullptr, nullptr, 2048, 8192, 1024, 2048, 1.0f,
      (long)S_LEN * S_LEN, (long)S_LEN, (long)S_LEN * E_DIM, 0, 0);
  // final = attn@Wo^T -> fp32 d_out  (M=8192,N=1024,K=1024)
  gemm_bt<false, true><<<dim3(8, 64, 1), blk, 0, stream>>>(
      attn, wob, d_out, nullptr, nullptr, 1024, 1024, 1024, 1024, 1.0f, 0, 0, 0, 0, 0);
}

// Round 3
// 511.370 us; speedup vs baseline: 1.3351x; 1.3351x over previous
//
#include <hip/hip_runtime.h>

// LoRA attention: B=4, S=2048, E=1024, R=16, fp32 in/out.
// bf16 MFMA (16x16x32) for all GEMMs, fp32 accumulate.
// R3 changes vs R2:
//  - prep_qkv is now PURE convert (the fused per-thread LoRA dot product was
//    240us: 16x re-reads, latency-bound at 7.7% VALU).
//  - LoRA T = X@A^T computed by a skinny MFMA GEMM (lora_t_mfma) reading
//    bf16 X once, no LDS (no cross-wave reuse), Am L1-resident. ~10us.
//  - A-matrices converted in cvt6 alongside B-matrices.

#define S_LEN 2048
#define E_DIM 1024

typedef __attribute__((ext_vector_type(8))) short short8;
typedef __attribute__((ext_vector_type(4))) float floatx4;

__device__ __forceinline__ unsigned short f2bf(float f) {
  union { float f; unsigned int u; } x; x.f = f;
  return (unsigned short)((x.u + 0x7fffu + ((x.u >> 16) & 1u)) >> 16);  // RNE
}
__device__ __forceinline__ float bf2f(unsigned short h) {
  union { unsigned int u; float f; } x; x.u = ((unsigned int)h) << 16;
  return x.f;
}

__device__ __forceinline__ void gld_lds16(const unsigned short* g, unsigned short* l) {
  __builtin_amdgcn_global_load_lds(
      (const __attribute__((address_space(1))) unsigned int*)(const void*)g,
      (__attribute__((address_space(3))) unsigned int*)(void*)l,
      16, 0, 0);
}

// C[m][n] = scale * (sum_k A[m][k]*B[n][k]  (+ LoRA: sum_r LA[m][r]*LB[n][r]))
// Fragment-major LDS tile layout: 16B chunk (row,kc) at chunk index
// (row>>4)*64 + kc*16 + (row&15) -> fragment ds_read_b128 is lane-contiguous
// (conflict-free); staging chunk = wave*64+lane sources row wave*16+(lane&15),
// kc (lane>>4)&3.
template<bool LORA, bool OUTF32>
__global__ __launch_bounds__(256) void gemm_bt(
    const unsigned short* __restrict__ A, const unsigned short* __restrict__ B,
    void* __restrict__ Cv,
    const unsigned short* __restrict__ LA, const unsigned short* __restrict__ LB,
    long lda, long ldb, long ldc, int K, float scale,
    long batA, long batB, long batC, long batLA, long batLB) {
  __shared__ alignas(16) unsigned short As[4096];  // 128 rows x 32 bf16
  __shared__ alignas(16) unsigned short Bs[4096];

  const int tid  = threadIdx.x;
  const int wave = tid >> 6, lane = tid & 63;
  const int quad = lane >> 4, l16 = lane & 15;
  const int wr = wave >> 1, wc = wave & 1;  // 2x2 waves, each 64x64
  const long m0 = (long)blockIdx.y * 128;
  const long n0 = (long)blockIdx.x * 128;
  A += (long)blockIdx.z * batA;
  B += (long)blockIdx.z * batB;

  floatx4 acc[4][4];
#pragma unroll
  for (int i = 0; i < 4; ++i)
#pragma unroll
    for (int j = 0; j < 4; ++j) acc[i][j] = (floatx4){0.f, 0.f, 0.f, 0.f};

  const long srow  = (long)((tid >> 6) * 16 + (tid & 15));
  const int  skoff = ((tid >> 4) & 3) * 8;
  const unsigned short* a_base = A + (m0 + srow) * lda + skoff;
  const unsigned short* b_base = B + (n0 + srow) * ldb + skoff;
  unsigned short* as0 = &As[wave * 512];
  unsigned short* as1 = &As[2048 + wave * 512];
  unsigned short* bs0 = &Bs[wave * 512];
  unsigned short* bs1 = &Bs[2048 + wave * 512];

  for (int k0 = 0; k0 < K; k0 += 32) {
    gld_lds16(a_base + k0, as0);
    gld_lds16(a_base + 64 * lda + k0, as1);
    gld_lds16(b_base + k0, bs0);
    gld_lds16(b_base + 64 * ldb + k0, bs1);
    __syncthreads();
    short8 afrag[4], bfrag[4];
#pragma unroll
    for (int i = 0; i < 4; ++i)
      afrag[i] = *(const short8*)&As[((wr * 4 + i) * 64 + lane) * 8];
#pragma unroll
    for (int j = 0; j < 4; ++j)
      bfrag[j] = *(const short8*)&Bs[((wc * 4 + j) * 64 + lane) * 8];
#pragma unroll
    for (int i = 0; i < 4; ++i)
#pragma unroll
      for (int j = 0; j < 4; ++j)
        acc[i][j] = __builtin_amdgcn_mfma_f32_16x16x32_bf16(afrag[i], bfrag[j], acc[i][j], 0, 0, 0);
    __syncthreads();
  }

  if constexpr (LORA) {
    const unsigned short* LAz = LA + (long)blockIdx.z * batLA;
    const unsigned short* LBz = LB + (long)blockIdx.z * batLB;
    const int r = tid >> 1, h = tid & 1;
    const int cbase = (r >> 4) * 64 + (r & 15) + h * 32;
    uint4* a0 = (uint4*)&As[cbase * 8];
    uint4* a1 = (uint4*)&As[(cbase + 16) * 8];
    uint4* b0 = (uint4*)&Bs[cbase * 8];
    uint4* b1 = (uint4*)&Bs[(cbase + 16) * 8];
    if (h == 0) {
      const uint4* sa = (const uint4*)(LAz + (m0 + r) * 16);
      a0[0] = sa[0]; a1[0] = sa[1];
      const uint4* sb = (const uint4*)(LBz + (n0 + r) * 16);
      b0[0] = sb[0]; b1[0] = sb[1];
    } else {
      uint4 z; z.x = z.y = z.z = z.w = 0u;
      a0[0] = z; a1[0] = z; b0[0] = z; b1[0] = z;
    }
    __syncthreads();
    short8 afrag[4], bfrag[4];
#pragma unroll
    for (int i = 0; i < 4; ++i)
      afrag[i] = *(const short8*)&As[((wr * 4 + i) * 64 + lane) * 8];
#pragma unroll
    for (int j = 0; j < 4; ++j)
      bfrag[j] = *(const short8*)&Bs[((wc * 4 + j) * 64 + lane) * 8];
#pragma unroll
    for (int i = 0; i < 4; ++i)
#pragma unroll
      for (int j = 0; j < 4; ++j)
        acc[i][j] = __builtin_amdgcn_mfma_f32_16x16x32_bf16(afrag[i], bfrag[j], acc[i][j], 0, 0, 0);
  }

#pragma unroll
  for (int i = 0; i < 4; ++i) {
    const long row = m0 + wr * 64 + i * 16 + quad * 4;
#pragma unroll
    for (int j = 0; j < 4; ++j) {
      const long col = n0 + wc * 64 + j * 16 + l16;
#pragma unroll
      for (int rr = 0; rr < 4; ++rr) {
        float val = acc[i][j][rr] * scale;
        if constexpr (OUTF32)
          ((float*)Cv)[(long)blockIdx.z * batC + (row + rr) * ldc + col] = val;
        else
          ((unsigned short*)Cv)[(long)blockIdx.z * batC + (row + rr) * ldc + col] = f2bf(val);
      }
    }
  }
}

__device__ __forceinline__ uint4 pack8(const float* x) {
  float4 a = *(const float4*)x;
  float4 b = *(const float4*)(x + 4);
  uint4 o;
  o.x = (unsigned int)f2bf(a.x) | ((unsigned int)f2bf(a.y) << 16);
  o.y = (unsigned int)f2bf(a.z) | ((unsigned int)f2bf(a.w) << 16);
  o.z = (unsigned int)f2bf(b.x) | ((unsigned int)f2bf(b.y) << 16);
  o.w = (unsigned int)f2bf(b.z) | ((unsigned int)f2bf(b.w) << 16);
  return o;
}

// pure fp32->bf16 convert of q/k/v. grid (512, 3), 16384 elems/block.
__global__ __launch_bounds__(256) void prep_qkv(
    const float* __restrict__ q, const float* __restrict__ k, const float* __restrict__ v,
    unsigned short* __restrict__ qb, unsigned short* __restrict__ kb,
    unsigned short* __restrict__ vb) {
  const float* X; unsigned short* Y;
  if (blockIdx.y == 0)      { X = q; Y = qb; }
  else if (blockIdx.y == 1) { X = k; Y = kb; }
  else                      { X = v; Y = vb; }
  const int tid = threadIdx.x;
  const long blk = (long)blockIdx.x * 16384;
#pragma unroll
  for (int it = 0; it < 8; ++it) {
    const long idx = blk + it * 2048 + tid * 8;
    *(uint4*)(Y + idx) = pack8(X + idx);
  }
}

// 4 weight matrices (1048576 elems each), grid (512, 4)
__global__ __launch_bounds__(256) void cvt4(
    const float* __restrict__ x0, const float* __restrict__ x1,
    const float* __restrict__ x2, const float* __restrict__ x3,
    unsigned short* __restrict__ y0, unsigned short* __restrict__ y1,
    unsigned short* __restrict__ y2, unsigned short* __restrict__ y3) {
  const float* x; unsigned short* y;
  switch (blockIdx.y) {
    case 0: x = x0; y = y0; break;
    case 1: x = x1; y = y1; break;
    case 2: x = x2; y = y2; break;
    default: x = x3; y = y3; break;
  }
  const long i = ((long)blockIdx.x * 256 + threadIdx.x) * 8;
  *(uint4*)(y + i) = pack8(x + i);
}

// 6 small matrices (16384 elems each): QB,KB,VB,QA,KA,VA. grid (8, 6)
__global__ __launch_bounds__(256) void cvt6(
    const float* __restrict__ x0, const float* __restrict__ x1, const float* __restrict__ x2,
    const float* __restrict__ x3, const float* __restrict__ x4, const float* __restrict__ x5,
    unsigned short* __restrict__ y0, unsigned short* __restrict__ y1, unsigned short* __restrict__ y2,
    unsigned short* __restrict__ y3, unsigned short* __restrict__ y4, unsigned short* __restrict__ y5) {
  const float* x; unsigned short* y;
  switch (blockIdx.y) {
    case 0: x = x0; y = y0; break;
    case 1: x = x1; y = y1; break;
    case 2: x = x2; y = y2; break;
    case 3: x = x3; y = y3; break;
    case 4: x = x4; y = y4; break;
    default: x = x5; y = y5; break;
  }
  const long i = ((long)blockIdx.x * 256 + threadIdx.x) * 8;
  *(uint4*)(y + i) = pack8(x + i);
}

// T[8192][16] = Xb @ Am^T via MFMA. grid (128, 3): 64 rows/block, 16/wave.
// No LDS: zero cross-wave reuse; Am (32KB bf16) is L1-resident after iter 0.
__global__ __launch_bounds__(256) void lora_t_mfma(
    const unsigned short* __restrict__ qb, const unsigned short* __restrict__ kb,
    const unsigned short* __restrict__ vb,
    const unsigned short* __restrict__ Aq, const unsigned short* __restrict__ Ak,
    const unsigned short* __restrict__ Av,
    unsigned short* __restrict__ Tq, unsigned short* __restrict__ Tk,
    unsigned short* __restrict__ Tv) {
  const unsigned short* X; const unsigned short* Am; unsigned short* T;
  if (blockIdx.y == 0)      { X = qb; Am = Aq; T = Tq; }
  else if (blockIdx.y == 1) { X = kb; Am = Ak; T = Tk; }
  else                      { X = vb; Am = Av; T = Tv; }
  const int tid = threadIdx.x, wave = tid >> 6, lane = tid & 63;
  const int quad = lane >> 4, l16 = lane & 15;
  const long m0 = (long)blockIdx.x * 64 + wave * 16;
  floatx4 acc = (floatx4){0.f, 0.f, 0.f, 0.f};
  const unsigned short* xp = X + (m0 + l16) * 1024 + quad * 8;
  const unsigned short* ap = Am + (long)l16 * 1024 + quad * 8;
#pragma unroll 4
  for (int k0 = 0; k0 < 1024; k0 += 32) {
    short8 af = *(const short8*)(xp + k0);
    short8 bf = *(const short8*)(ap + k0);
    acc = __builtin_amdgcn_mfma_f32_16x16x32_bf16(af, bf, acc, 0, 0, 0);
  }
#pragma unroll
  for (int rr = 0; rr < 4; ++rr)
    T[(m0 + quad * 4 + rr) * 16 + l16] = f2bf(acc[rr]);
}

// in-place row softmax over 2048 bf16 scores; one block per row
__global__ __launch_bounds__(256) void softmax_kernel(unsigned short* __restrict__ S) {
  const long base = (long)blockIdx.x * 2048;
  const int tid = threadIdx.x;
  const int lane = tid & 63, wave = tid >> 6;
  __shared__ float redm[4], reds[4];
  uint4 raw = *(const uint4*)(S + base + tid * 8);
  unsigned int w[4] = {raw.x, raw.y, raw.z, raw.w};
  float v[8];
#pragma unroll
  for (int i = 0; i < 4; ++i) {
    v[2 * i]     = bf2f((unsigned short)(w[i] & 0xffffu));
    v[2 * i + 1] = bf2f((unsigned short)(w[i] >> 16));
  }
  float m = v[0];
#pragma unroll
  for (int i = 1; i < 8; ++i) m = fmaxf(m, v[i]);
  for (int off = 32; off >= 1; off >>= 1) m = fmaxf(m, __shfl_xor(m, off, 64));
  if (lane == 0) redm[wave] = m;
  __syncthreads();
  m = fmaxf(fmaxf(redm[0], redm[1]), fmaxf(redm[2], redm[3]));
  float e[8], s = 0.f;
#pragma unroll
  for (int i = 0; i < 8; ++i) { e[i] = __expf(v[i] - m); s += e[i]; }
  for (int off = 32; off >= 1; off >>= 1) s += __shfl_xor(s, off, 64);
  if (lane == 0) reds[wave] = s;
  __syncthreads();
  s = reds[0] + reds[1] + reds[2] + reds[3];
  const float inv = 1.0f / s;
  uint4 o;
  o.x = (unsigned int)f2bf(e[0] * inv) | ((unsigned int)f2bf(e[1] * inv) << 16);
  o.y = (unsigned int)f2bf(e[2] * inv) | ((unsigned int)f2bf(e[3] * inv) << 16);
  o.z = (unsigned int)f2bf(e[4] * inv) | ((unsigned int)f2bf(e[5] * inv) << 16);
  o.w = (unsigned int)f2bf(e[6] * inv) | ((unsigned int)f2bf(e[7] * inv) << 16);
  *(uint4*)(S + base + tid * 8) = o;
}

extern "C" void kernel_launch(void* const* d_in, const int* in_sizes, int n_in,
                              void* d_out, int out_size, void* d_ws, size_t ws_size,
                              hipStream_t stream) {
  const float* q  = (const float*)d_in[0];
  const float* k  = (const float*)d_in[1];
  const float* v  = (const float*)d_in[2];
  const float* Wq = (const float*)d_in[3];
  const float* Wk = (const float*)d_in[4];
  const float* Wv = (const float*)d_in[5];
  const float* QA = (const float*)d_in[6];
  const float* QB = (const float*)d_in[7];
  const float* KA = (const float*)d_in[8];
  const float* KB = (const float*)d_in[9];
  const float* VA = (const float*)d_in[10];
  const float* VB = (const float*)d_in[11];
  const float* Wo = (const float*)d_in[12];

  unsigned short* W = (unsigned short*)d_ws;
  const long SEe = (long)8192 * 1024;  // 8388608
  unsigned short* qb  = W;             // dead after Q-proj -> scores low half
  unsigned short* kb  = W + SEe;
  unsigned short* vb  = W + 2 * SEe;   // dead after V-proj -> attn buffer
  unsigned short* Qp  = W + 3 * SEe;
  unsigned short* Kp  = W + 4 * SEe;
  unsigned short* VT  = W + 5 * SEe;   // [1024][8192] = V^T
  unsigned short* wqb = W + 6 * SEe;
  unsigned short* wkb = wqb + 1048576;
  unsigned short* wvb = wkb + 1048576;
  unsigned short* wob = wvb + 1048576;
  unsigned short* Bqb = wob + 1048576;
  unsigned short* Bkb = Bqb + 16384;
  unsigned short* Bvb = Bkb + 16384;
  unsigned short* Aqb = Bvb + 16384;
  unsigned short* Akb = Aqb + 16384;
  unsigned short* Avb = Akb + 16384;
  unsigned short* Tq  = Avb + 16384;   // [8192][16]
  unsigned short* Tk  = Tq + 131072;
  unsigned short* Tv  = Tk + 131072;
  unsigned short* scores = W;          // [4][2048][2048] bf16, aliases qb+kb
  unsigned short* attn   = vb;         // [8192][1024] bf16, aliases vb

  dim3 blk(256, 1, 1);
  prep_qkv<<<dim3(512, 3, 1), blk, 0, stream>>>(q, k, v, qb, kb, vb);
  cvt4<<<dim3(512, 4, 1), blk, 0, stream>>>(Wq, Wk, Wv, Wo, wqb, wkb, wvb, wob);
  cvt6<<<dim3(8, 6, 1), blk, 0, stream>>>(QB, KB, VB, QA, KA, VA,
                                          Bqb, Bkb, Bvb, Aqb, Akb, Avb);
  lora_t_mfma<<<dim3(128, 3, 1), blk, 0, stream>>>(qb, kb, vb, Aqb, Akb, Avb, Tq, Tk, Tv);

  // Q = qb@Wq^T + Tq@Bq^T ; K likewise (z batches both; M=8192,N=1024,K=1024)
  gemm_bt<true, false><<<dim3(8, 64, 2), blk, 0, stream>>>(
      qb, wqb, Qp, Tq, Bqb, 1024, 1024, 1024, 1024, 1.0f,
      SEe, 1048576, SEe, 131072, 16384);
  // VT = Wv@vb^T + Bv@Tv^T  (M=1024,N=8192, C row-stride 8192)
  gemm_bt<true, false><<<dim3(64, 8, 1), blk, 0, stream>>>(
      wvb, vb, VT, Bvb, Tv, 1024, 1024, 8192, 1024, 1.0f, 0, 0, 0, 0, 0);
  // scores = Qp@Kp^T / 32   (batched, M=N=2048,K=1024)
  gemm_bt<false, false><<<dim3(16, 16, 4), blk, 0, stream>>>(
      Qp, Kp, scores, nullptr, nullptr, 1024, 1024, 2048, 1024, 0.03125f,
      (long)S_LEN * E_DIM, (long)S_LEN * E_DIM, (long)S_LEN * S_LEN, 0, 0);
  softmax_kernel<<<8192, blk, 0, stream>>>(scores);
  // attn_out = P@V = P@(VT)^T  (batched, M=2048,N=1024,K=2048)
  gemm_bt<false, false><<<dim3(8, 16, 4), blk, 0, stream>>>(
      scores, VT, attn, nullptr, nullptr, 2048, 8192, 1024, 2048, 1.0f,
      (long)S_LEN * S_LEN, (long)S_LEN, (long)S_LEN * E_DIM, 0, 0);
  // final = attn@Wo^T -> fp32 d_out  (M=8192,N=1024,K=1024)
  gemm_bt<false, true><<<dim3(8, 64, 1), blk, 0, stream>>>(
      attn, wob, d_out, nullptr, nullptr, 1024, 1024, 1024, 1024, 1.0f, 0, 0, 0, 0, 0);
}

// Round 4
// 499.705 us; speedup vs baseline: 1.3663x; 1.0233x over previous
//
#include <hip/hip_runtime.h>

// LoRA attention: B=4, S=2048, E=1024, R=16, fp32 in/out.
// bf16 MFMA (16x16x32) for all GEMMs, fp32 accumulate.
// R4 changes vs R3:
//  - XCD-aware block swizzle in gemm_bt. HW assigns XCD = flat_wg % 8, and the
//    old x-major order put the SAME A-tile on all 8 XCDs (8x L2 duplication:
//    FETCH 136 MB vs 37 MB ideal on the Q/K GEMM). New mapping: each XCD owns
//    a contiguous M-chunk (OWNM) or N-chunk (OWNN, for the wide V-proj) and
//    sweeps the other dim fastest -> per-XCD working set ~4 MB (= L2), large
//    operand fetched once chip-wide, small operand dup absorbed by L3.

#define S_LEN 2048
#define E_DIM 1024

typedef __attribute__((ext_vector_type(8))) short short8;
typedef __attribute__((ext_vector_type(4))) float floatx4;

__device__ __forceinline__ unsigned short f2bf(float f) {
  union { float f; unsigned int u; } x; x.f = f;
  return (unsigned short)((x.u + 0x7fffu + ((x.u >> 16) & 1u)) >> 16);  // RNE
}
__device__ __forceinline__ float bf2f(unsigned short h) {
  union { unsigned int u; float f; } x; x.u = ((unsigned int)h) << 16;
  return x.f;
}

__device__ __forceinline__ void gld_lds16(const unsigned short* g, unsigned short* l) {
  __builtin_amdgcn_global_load_lds(
      (const __attribute__((address_space(1))) unsigned int*)(const void*)g,
      (__attribute__((address_space(3))) unsigned int*)(void*)l,
      16, 0, 0);
}

// C[m][n] = scale * (sum_k A[m][k]*B[n][k]  (+ LoRA: sum_r LA[m][r]*LB[n][r]))
// Fragment-major LDS tile layout: 16B chunk (row,kc) at chunk index
// (row>>4)*64 + kc*16 + (row&15) -> fragment ds_read_b128 is lane-contiguous
// (conflict-free). grid dims must be powers of two, gridDim.x*gridDim.y % 8 == 0,
// and the owned dim a multiple of 8 tiles.
template<bool LORA, bool OUTF32, bool OWNM>
__global__ __launch_bounds__(256) void gemm_bt(
    const unsigned short* __restrict__ A, const unsigned short* __restrict__ B,
    void* __restrict__ Cv,
    const unsigned short* __restrict__ LA, const unsigned short* __restrict__ LB,
    long lda, long ldb, long ldc, int K, float scale,
    long batA, long batB, long batC, long batLA, long batLB) {
  __shared__ alignas(16) unsigned short As[4096];  // 128 rows x 32 bf16
  __shared__ alignas(16) unsigned short Bs[4096];

  const int tid  = threadIdx.x;
  const int wave = tid >> 6, lane = tid & 63;
  const int quad = lane >> 4, l16 = lane & 15;
  const int wr = wave >> 1, wc = wave & 1;  // 2x2 waves, each 64x64

  // XCD-aware swizzle: xcd = flat%8 owns a chunk of the M (or N) tiles and
  // sweeps the other dimension fastest (B [or A] streams through its L2).
  const int Nx = (int)gridDim.x, Ny = (int)gridDim.y;
  const int wg2 = (int)blockIdx.x + Nx * (int)blockIdx.y;
  const int xcd = wg2 & 7, ii = wg2 >> 3;
  int bx, by;
  if constexpr (OWNM) {
    const int lg = 31 - __clz(Nx);
    by = xcd * (Ny >> 3) + (ii >> lg);
    bx = ii & (Nx - 1);
  } else {
    const int lg = 31 - __clz(Ny);
    bx = xcd * (Nx >> 3) + (ii >> lg);
    by = ii & (Ny - 1);
  }
  const long m0 = (long)by * 128;
  const long n0 = (long)bx * 128;
  A += (long)blockIdx.z * batA;
  B += (long)blockIdx.z * batB;

  floatx4 acc[4][4];
#pragma unroll
  for (int i = 0; i < 4; ++i)
#pragma unroll
    for (int j = 0; j < 4; ++j) acc[i][j] = (floatx4){0.f, 0.f, 0.f, 0.f};

  const long srow  = (long)((tid >> 6) * 16 + (tid & 15));
  const int  skoff = ((tid >> 4) & 3) * 8;
  const unsigned short* a_base = A + (m0 + srow) * lda + skoff;
  const unsigned short* b_base = B + (n0 + srow) * ldb + skoff;
  unsigned short* as0 = &As[wave * 512];
  unsigned short* as1 = &As[2048 + wave * 512];
  unsigned short* bs0 = &Bs[wave * 512];
  unsigned short* bs1 = &Bs[2048 + wave * 512];

  for (int k0 = 0; k0 < K; k0 += 32) {
    gld_lds16(a_base + k0, as0);
    gld_lds16(a_base + 64 * lda + k0, as1);
    gld_lds16(b_base + k0, bs0);
    gld_lds16(b_base + 64 * ldb + k0, bs1);
    __syncthreads();
    short8 afrag[4], bfrag[4];
#pragma unroll
    for (int i = 0; i < 4; ++i)
      afrag[i] = *(const short8*)&As[((wr * 4 + i) * 64 + lane) * 8];
#pragma unroll
    for (int j = 0; j < 4; ++j)
      bfrag[j] = *(const short8*)&Bs[((wc * 4 + j) * 64 + lane) * 8];
#pragma unroll
    for (int i = 0; i < 4; ++i)
#pragma unroll
      for (int j = 0; j < 4; ++j)
        acc[i][j] = __builtin_amdgcn_mfma_f32_16x16x32_bf16(afrag[i], bfrag[j], acc[i][j], 0, 0, 0);
    __syncthreads();
  }

  if constexpr (LORA) {
    const unsigned short* LAz = LA + (long)blockIdx.z * batLA;
    const unsigned short* LBz = LB + (long)blockIdx.z * batLB;
    const int r = tid >> 1, h = tid & 1;
    const int cbase = (r >> 4) * 64 + (r & 15) + h * 32;
    uint4* a0 = (uint4*)&As[cbase * 8];
    uint4* a1 = (uint4*)&As[(cbase + 16) * 8];
    uint4* b0 = (uint4*)&Bs[cbase * 8];
    uint4* b1 = (uint4*)&Bs[(cbase + 16) * 8];
    if (h == 0) {
      const uint4* sa = (const uint4*)(LAz + (m0 + r) * 16);
      a0[0] = sa[0]; a1[0] = sa[1];
      const uint4* sb = (const uint4*)(LBz + (n0 + r) * 16);
      b0[0] = sb[0]; b1[0] = sb[1];
    } else {
      uint4 z; z.x = z.y = z.z = z.w = 0u;
      a0[0] = z; a1[0] = z; b0[0] = z; b1[0] = z;
    }
    __syncthreads();
    short8 afrag[4], bfrag[4];
#pragma unroll
    for (int i = 0; i < 4; ++i)
      afrag[i] = *(const short8*)&As[((wr * 4 + i) * 64 + lane) * 8];
#pragma unroll
    for (int j = 0; j < 4; ++j)
      bfrag[j] = *(const short8*)&Bs[((wc * 4 + j) * 64 + lane) * 8];
#pragma unroll
    for (int i = 0; i < 4; ++i)
#pragma unroll
      for (int j = 0; j < 4; ++j)
        acc[i][j] = __builtin_amdgcn_mfma_f32_16x16x32_bf16(afrag[i], bfrag[j], acc[i][j], 0, 0, 0);
  }

#pragma unroll
  for (int i = 0; i < 4; ++i) {
    const long row = m0 + wr * 64 + i * 16 + quad * 4;
#pragma unroll
    for (int j = 0; j < 4; ++j) {
      const long col = n0 + wc * 64 + j * 16 + l16;
#pragma unroll
      for (int rr = 0; rr < 4; ++rr) {
        float val = acc[i][j][rr] * scale;
        if constexpr (OUTF32)
          ((float*)Cv)[(long)blockIdx.z * batC + (row + rr) * ldc + col] = val;
        else
          ((unsigned short*)Cv)[(long)blockIdx.z * batC + (row + rr) * ldc + col] = f2bf(val);
      }
    }
  }
}

__device__ __forceinline__ uint4 pack8(const float* x) {
  float4 a = *(const float4*)x;
  float4 b = *(const float4*)(x + 4);
  uint4 o;
  o.x = (unsigned int)f2bf(a.x) | ((unsigned int)f2bf(a.y) << 16);
  o.y = (unsigned int)f2bf(a.z) | ((unsigned int)f2bf(a.w) << 16);
  o.z = (unsigned int)f2bf(b.x) | ((unsigned int)f2bf(b.y) << 16);
  o.w = (unsigned int)f2bf(b.z) | ((unsigned int)f2bf(b.w) << 16);
  return o;
}

// pure fp32->bf16 convert of q/k/v. grid (512, 3), 16384 elems/block.
__global__ __launch_bounds__(256) void prep_qkv(
    const float* __restrict__ q, const float* __restrict__ k, const float* __restrict__ v,
    unsigned short* __restrict__ qb, unsigned short* __restrict__ kb,
    unsigned short* __restrict__ vb) {
  const float* X; unsigned short* Y;
  if (blockIdx.y == 0)      { X = q; Y = qb; }
  else if (blockIdx.y == 1) { X = k; Y = kb; }
  else                      { X = v; Y = vb; }
  const int tid = threadIdx.x;
  const long blk = (long)blockIdx.x * 16384;
#pragma unroll
  for (int it = 0; it < 8; ++it) {
    const long idx = blk + it * 2048 + tid * 8;
    *(uint4*)(Y + idx) = pack8(X + idx);
  }
}

// 4 weight matrices (1048576 elems each), grid (512, 4)
__global__ __launch_bounds__(256) void cvt4(
    const float* __restrict__ x0, const float* __restrict__ x1,
    const float* __restrict__ x2, const float* __restrict__ x3,
    unsigned short* __restrict__ y0, unsigned short* __restrict__ y1,
    unsigned short* __restrict__ y2, unsigned short* __restrict__ y3) {
  const float* x; unsigned short* y;
  switch (blockIdx.y) {
    case 0: x = x0; y = y0; break;
    case 1: x = x1; y = y1; break;
    case 2: x = x2; y = y2; break;
    default: x = x3; y = y3; break;
  }
  const long i = ((long)blockIdx.x * 256 + threadIdx.x) * 8;
  *(uint4*)(y + i) = pack8(x + i);
}

// 6 small matrices (16384 elems each): QB,KB,VB,QA,KA,VA. grid (8, 6)
__global__ __launch_bounds__(256) void cvt6(
    const float* __restrict__ x0, const float* __restrict__ x1, const float* __restrict__ x2,
    const float* __restrict__ x3, const float* __restrict__ x4, const float* __restrict__ x5,
    unsigned short* __restrict__ y0, unsigned short* __restrict__ y1, unsigned short* __restrict__ y2,
    unsigned short* __restrict__ y3, unsigned short* __restrict__ y4, unsigned short* __restrict__ y5) {
  const float* x; unsigned short* y;
  switch (blockIdx.y) {
    case 0: x = x0; y = y0; break;
    case 1: x = x1; y = y1; break;
    case 2: x = x2; y = y2; break;
    case 3: x = x3; y = y3; break;
    case 4: x = x4; y = y4; break;
    default: x = x5; y = y5; break;
  }
  const long i = ((long)blockIdx.x * 256 + threadIdx.x) * 8;
  *(uint4*)(y + i) = pack8(x + i);
}

// T[8192][16] = Xb @ Am^T via MFMA. grid (128, 3): 64 rows/block, 16/wave.
__global__ __launch_bounds__(256) void lora_t_mfma(
    const unsigned short* __restrict__ qb, const unsigned short* __restrict__ kb,
    const unsigned short* __restrict__ vb,
    const unsigned short* __restrict__ Aq, const unsigned short* __restrict__ Ak,
    const unsigned short* __restrict__ Av,
    unsigned short* __restrict__ Tq, unsigned short* __restrict__ Tk,
    unsigned short* __restrict__ Tv) {
  const unsigned short* X; const unsigned short* Am; unsigned short* T;
  if (blockIdx.y == 0)      { X = qb; Am = Aq; T = Tq; }
  else if (blockIdx.y == 1) { X = kb; Am = Ak; T = Tk; }
  else                      { X = vb; Am = Av; T = Tv; }
  const int tid = threadIdx.x, wave = tid >> 6, lane = tid & 63;
  const int quad = lane >> 4, l16 = lane & 15;
  const long m0 = (long)blockIdx.x * 64 + wave * 16;
  floatx4 acc = (floatx4){0.f, 0.f, 0.f, 0.f};
  const unsigned short* xp = X + (m0 + l16) * 1024 + quad * 8;
  const unsigned short* ap = Am + (long)l16 * 1024 + quad * 8;
#pragma unroll 4
  for (int k0 = 0; k0 < 1024; k0 += 32) {
    short8 af = *(const short8*)(xp + k0);
    short8 bf = *(const short8*)(ap + k0);
    acc = __builtin_amdgcn_mfma_f32_16x16x32_bf16(af, bf, acc, 0, 0, 0);
  }
#pragma unroll
  for (int rr = 0; rr < 4; ++rr)
    T[(m0 + quad * 4 + rr) * 16 + l16] = f2bf(acc[rr]);
}

// in-place row softmax over 2048 bf16 scores; one block per row
__global__ __launch_bounds__(256) void softmax_kernel(unsigned short* __restrict__ S) {
  const long base = (long)blockIdx.x * 2048;
  const int tid = threadIdx.x;
  const int lane = tid & 63, wave = tid >> 6;
  __shared__ float redm[4], reds[4];
  uint4 raw = *(const uint4*)(S + base + tid * 8);
  unsigned int w[4] = {raw.x, raw.y, raw.z, raw.w};
  float v[8];
#pragma unroll
  for (int i = 0; i < 4; ++i) {
    v[2 * i]     = bf2f((unsigned short)(w[i] & 0xffffu));
    v[2 * i + 1] = bf2f((unsigned short)(w[i] >> 16));
  }
  float m = v[0];
#pragma unroll
  for (int i = 1; i < 8; ++i) m = fmaxf(m, v[i]);
  for (int off = 32; off >= 1; off >>= 1) m = fmaxf(m, __shfl_xor(m, off, 64));
  if (lane == 0) redm[wave] = m;
  __syncthreads();
  m = fmaxf(fmaxf(redm[0], redm[1]), fmaxf(redm[2], redm[3]));
  float e[8], s = 0.f;
#pragma unroll
  for (int i = 0; i < 8; ++i) { e[i] = __expf(v[i] - m); s += e[i]; }
  for (int off = 32; off >= 1; off >>= 1) s += __shfl_xor(s, off, 64);
  if (lane == 0) reds[wave] = s;
  __syncthreads();
  s = reds[0] + reds[1] + reds[2] + reds[3];
  const float inv = 1.0f / s;
  uint4 o;
  o.x = (unsigned int)f2bf(e[0] * inv) | ((unsigned int)f2bf(e[1] * inv) << 16);
  o.y = (unsigned int)f2bf(e[2] * inv) | ((unsigned int)f2bf(e[3] * inv) << 16);
  o.z = (unsigned int)f2bf(e[4] * inv) | ((unsigned int)f2bf(e[5] * inv) << 16);
  o.w = (unsigned int)f2bf(e[6] * inv) | ((unsigned int)f2bf(e[7] * inv) << 16);
  *(uint4*)(S + base + tid * 8) = o;
}

extern "C" void kernel_launch(void* const* d_in, const int* in_sizes, int n_in,
                              void* d_out, int out_size, void* d_ws, size_t ws_size,
                              hipStream_t stream) {
  const float* q  = (const float*)d_in[0];
  const float* k  = (const float*)d_in[1];
  const float* v  = (const float*)d_in[2];
  const float* Wq = (const float*)d_in[3];
  const float* Wk = (const float*)d_in[4];
  const float* Wv = (const float*)d_in[5];
  const float* QA = (const float*)d_in[6];
  const float* QB = (const float*)d_in[7];
  const float* KA = (const float*)d_in[8];
  const float* KB = (const float*)d_in[9];
  const float* VA = (const float*)d_in[10];
  const float* VB = (const float*)d_in[11];
  const float* Wo = (const float*)d_in[12];

  unsigned short* W = (unsigned short*)d_ws;
  const long SEe = (long)8192 * 1024;  // 8388608
  unsigned short* qb  = W;             // dead after Q-proj -> scores low half
  unsigned short* kb  = W + SEe;
  unsigned short* vb  = W + 2 * SEe;   // dead after V-proj -> attn buffer
  unsigned short* Qp  = W + 3 * SEe;
  unsigned short* Kp  = W + 4 * SEe;
  unsigned short* VT  = W + 5 * SEe;   // [1024][8192] = V^T
  unsigned short* wqb = W + 6 * SEe;
  unsigned short* wkb = wqb + 1048576;
  unsigned short* wvb = wkb + 1048576;
  unsigned short* wob = wvb + 1048576;
  unsigned short* Bqb = wob + 1048576;
  unsigned short* Bkb = Bqb + 16384;
  unsigned short* Bvb = Bkb + 16384;
  unsigned short* Aqb = Bvb + 16384;
  unsigned short* Akb = Aqb + 16384;
  unsigned short* Avb = Akb + 16384;
  unsigned short* Tq  = Avb + 16384;   // [8192][16]
  unsigned short* Tk  = Tq + 131072;
  unsigned short* Tv  = Tk + 131072;
  unsigned short* scores = W;          // [4][2048][2048] bf16, aliases qb+kb
  unsigned short* attn   = vb;         // [8192][1024] bf16, aliases vb

  dim3 blk(256, 1, 1);
  prep_qkv<<<dim3(512, 3, 1), blk, 0, stream>>>(q, k, v, qb, kb, vb);
  cvt4<<<dim3(512, 4, 1), blk, 0, stream>>>(Wq, Wk, Wv, Wo, wqb, wkb, wvb, wob);
  cvt6<<<dim3(8, 6, 1), blk, 0, stream>>>(QB, KB, VB, QA, KA, VA,
                                          Bqb, Bkb, Bvb, Aqb, Akb, Avb);
  lora_t_mfma<<<dim3(128, 3, 1), blk, 0, stream>>>(qb, kb, vb, Aqb, Akb, Avb, Tq, Tk, Tv);

  // Q = qb@Wq^T + Tq@Bq^T ; K likewise (z batches; M=8192,N=1024,K=1024)
  // OWNM: XCD owns M-chunk of activations, streams 2MB weight B.
  gemm_bt<true, false, true><<<dim3(8, 64, 2), blk, 0, stream>>>(
      qb, wqb, Qp, Tq, Bqb, 1024, 1024, 1024, 1024, 1.0f,
      SEe, 1048576, SEe, 131072, 16384);
  // VT = Wv@vb^T + Bv@Tv^T  (M=1024,N=8192): OWNN (partition wide N, stream 2MB A)
  gemm_bt<true, false, false><<<dim3(64, 8, 1), blk, 0, stream>>>(
      wvb, vb, VT, Bvb, Tv, 1024, 1024, 8192, 1024, 1.0f, 0, 0, 0, 0, 0);
  // scores = Qp@Kp^T / 32   (batched, M=N=2048,K=1024)
  gemm_bt<false, false, true><<<dim3(16, 16, 4), blk, 0, stream>>>(
      Qp, Kp, scores, nullptr, nullptr, 1024, 1024, 2048, 1024, 0.03125f,
      (long)S_LEN * E_DIM, (long)S_LEN * E_DIM, (long)S_LEN * S_LEN, 0, 0);
  softmax_kernel<<<8192, blk, 0, stream>>>(scores);
  // attn_out = P@V = P@(VT)^T  (batched, M=2048,N=1024,K=2048)
  gemm_bt<false, false, true><<<dim3(8, 16, 4), blk, 0, stream>>>(
      scores, VT, attn, nullptr, nullptr, 2048, 8192, 1024, 2048, 1.0f,
      (long)S_LEN * S_LEN, (long)S_LEN, (long)S_LEN * E_DIM, 0, 0);
  // final = attn@Wo^T -> fp32 d_out  (M=8192,N=1024,K=1024)
  gemm_bt<false, true, true><<<dim3(8, 64, 1), blk, 0, stream>>>(
      attn, wob, d_out, nullptr, nullptr, 1024, 1024, 1024, 1024, 1.0f, 0, 0, 0, 0, 0);
}

// Round 5
// 486.937 us; speedup vs baseline: 1.4021x; 1.0262x over previous
//
#include <hip/hip_runtime.h>

// LoRA attention: B=4, S=2048, E=1024, R=16, fp32 in/out.
// bf16 MFMA (16x16x32) for all GEMMs, fp32 accumulate.
// R5 changes vs R4:
//  - Double-buffered K-loop in gemm_bt: loads for iter t+1 issued right after
//    the (single) barrier, before compute of iter t, so the ~500cyc
//    global_load_lds latency overlaps compute instead of being exposed at
//    every barrier (R4: MfmaUtil 15.7%, ~3100 cyc/iter vs ~300 cyc MFMA).
//    LDS 16->32 KB (still 5 blocks/CU by LDS).
//  - cvt4+cvt6 merged into one cvt_all dispatch.
// Carried: fragment-major LDS layout (0 bank conflicts), XCD-aware swizzle
// (FETCH at ideal: 41.6 MB on Q/K GEMM).

#define S_LEN 2048
#define E_DIM 1024

typedef __attribute__((ext_vector_type(8))) short short8;
typedef __attribute__((ext_vector_type(4))) float floatx4;

__device__ __forceinline__ unsigned short f2bf(float f) {
  union { float f; unsigned int u; } x; x.f = f;
  return (unsigned short)((x.u + 0x7fffu + ((x.u >> 16) & 1u)) >> 16);  // RNE
}
__device__ __forceinline__ float bf2f(unsigned short h) {
  union { unsigned int u; float f; } x; x.u = ((unsigned int)h) << 16;
  return x.f;
}

__device__ __forceinline__ void gld_lds16(const unsigned short* g, unsigned short* l) {
  __builtin_amdgcn_global_load_lds(
      (const __attribute__((address_space(1))) unsigned int*)(const void*)g,
      (__attribute__((address_space(3))) unsigned int*)(void*)l,
      16, 0, 0);
}

// C[m][n] = scale * (sum_k A[m][k]*B[n][k]  (+ LoRA: sum_r LA[m][r]*LB[n][r]))
// Fragment-major LDS tile layout: 16B chunk (row,kc) at chunk index
// (row>>4)*64 + kc*16 + (row&15) -> fragment ds_read_b128 is lane-contiguous.
// Grid dims powers of two; owned dim a multiple of 8 tiles.
template<bool LORA, bool OUTF32, bool OWNM>
__global__ __launch_bounds__(256) void gemm_bt(
    const unsigned short* __restrict__ A, const unsigned short* __restrict__ B,
    void* __restrict__ Cv,
    const unsigned short* __restrict__ LA, const unsigned short* __restrict__ LB,
    long lda, long ldb, long ldc, int K, float scale,
    long batA, long batB, long batC, long batLA, long batLB) {
  __shared__ alignas(16) unsigned short As[2][4096];  // 2 x (128 rows x 32 bf16)
  __shared__ alignas(16) unsigned short Bs[2][4096];

  const int tid  = threadIdx.x;
  const int wave = tid >> 6, lane = tid & 63;
  const int quad = lane >> 4, l16 = lane & 15;
  const int wr = wave >> 1, wc = wave & 1;  // 2x2 waves, each 64x64

  // XCD-aware swizzle: xcd = flat%8 owns a chunk of the M (or N) tiles and
  // sweeps the other dimension fastest.
  const int Nx = (int)gridDim.x, Ny = (int)gridDim.y;
  const int wg2 = (int)blockIdx.x + Nx * (int)blockIdx.y;
  const int xcd = wg2 & 7, ii = wg2 >> 3;
  int bx, by;
  if constexpr (OWNM) {
    const int lg = 31 - __clz(Nx);
    by = xcd * (Ny >> 3) + (ii >> lg);
    bx = ii & (Nx - 1);
  } else {
    const int lg = 31 - __clz(Ny);
    bx = xcd * (Nx >> 3) + (ii >> lg);
    by = ii & (Ny - 1);
  }
  const long m0 = (long)by * 128;
  const long n0 = (long)bx * 128;
  A += (long)blockIdx.z * batA;
  B += (long)blockIdx.z * batB;

  floatx4 acc[4][4];
#pragma unroll
  for (int i = 0; i < 4; ++i)
#pragma unroll
    for (int j = 0; j < 4; ++j) acc[i][j] = (floatx4){0.f, 0.f, 0.f, 0.f};

  const long srow  = (long)((tid >> 6) * 16 + (tid & 15));
  const int  skoff = ((tid >> 4) & 3) * 8;
  const unsigned short* a_base = A + (m0 + srow) * lda + skoff;
  const unsigned short* b_base = B + (n0 + srow) * ldb + skoff;
  const int lo = wave * 512;

  // prologue: stage k-chunk 0 into buffer 0
  gld_lds16(a_base, &As[0][lo]);
  gld_lds16(a_base + 64 * lda, &As[0][2048 + lo]);
  gld_lds16(b_base, &Bs[0][lo]);
  gld_lds16(b_base + 64 * ldb, &Bs[0][2048 + lo]);

  const int niter = K >> 5;
#pragma unroll 2
  for (int it = 0; it < niter; ++it) {
    const int cur = it & 1;
    __syncthreads();  // drains vmcnt for buf cur (loads had prev compute to fly)
    if (it + 1 < niter) {
      const int k1 = (it + 1) << 5;
      gld_lds16(a_base + k1, &As[cur ^ 1][lo]);
      gld_lds16(a_base + 64 * lda + k1, &As[cur ^ 1][2048 + lo]);
      gld_lds16(b_base + k1, &Bs[cur ^ 1][lo]);
      gld_lds16(b_base + 64 * ldb + k1, &Bs[cur ^ 1][2048 + lo]);
    }
    short8 afrag[4], bfrag[4];
#pragma unroll
    for (int i = 0; i < 4; ++i)
      afrag[i] = *(const short8*)&As[cur][((wr * 4 + i) * 64 + lane) * 8];
#pragma unroll
    for (int j = 0; j < 4; ++j)
      bfrag[j] = *(const short8*)&Bs[cur][((wc * 4 + j) * 64 + lane) * 8];
#pragma unroll
    for (int i = 0; i < 4; ++i)
#pragma unroll
      for (int j = 0; j < 4; ++j)
        acc[i][j] = __builtin_amdgcn_mfma_f32_16x16x32_bf16(afrag[i], bfrag[j], acc[i][j], 0, 0, 0);
  }

  if constexpr (LORA) {
    __syncthreads();  // last compute's ds_reads done before overwrite
    const unsigned short* LAz = LA + (long)blockIdx.z * batLA;
    const unsigned short* LBz = LB + (long)blockIdx.z * batLB;
    const int r = tid >> 1, h = tid & 1;
    const int cbase = (r >> 4) * 64 + (r & 15) + h * 32;
    uint4* a0 = (uint4*)&As[0][cbase * 8];
    uint4* a1 = (uint4*)&As[0][(cbase + 16) * 8];
    uint4* b0 = (uint4*)&Bs[0][cbase * 8];
    uint4* b1 = (uint4*)&Bs[0][(cbase + 16) * 8];
    if (h == 0) {
      const uint4* sa = (const uint4*)(LAz + (m0 + r) * 16);
      a0[0] = sa[0]; a1[0] = sa[1];
      const uint4* sb = (const uint4*)(LBz + (n0 + r) * 16);
      b0[0] = sb[0]; b1[0] = sb[1];
    } else {
      uint4 z; z.x = z.y = z.z = z.w = 0u;
      a0[0] = z; a1[0] = z; b0[0] = z; b1[0] = z;
    }
    __syncthreads();
    short8 afrag[4], bfrag[4];
#pragma unroll
    for (int i = 0; i < 4; ++i)
      afrag[i] = *(const short8*)&As[0][((wr * 4 + i) * 64 + lane) * 8];
#pragma unroll
    for (int j = 0; j < 4; ++j)
      bfrag[j] = *(const short8*)&Bs[0][((wc * 4 + j) * 64 + lane) * 8];
#pragma unroll
    for (int i = 0; i < 4; ++i)
#pragma unroll
      for (int j = 0; j < 4; ++j)
        acc[i][j] = __builtin_amdgcn_mfma_f32_16x16x32_bf16(afrag[i], bfrag[j], acc[i][j], 0, 0, 0);
  }

#pragma unroll
  for (int i = 0; i < 4; ++i) {
    const long row = m0 + wr * 64 + i * 16 + quad * 4;
#pragma unroll
    for (int j = 0; j < 4; ++j) {
      const long col = n0 + wc * 64 + j * 16 + l16;
#pragma unroll
      for (int rr = 0; rr < 4; ++rr) {
        float val = acc[i][j][rr] * scale;
        if constexpr (OUTF32)
          ((float*)Cv)[(long)blockIdx.z * batC + (row + rr) * ldc + col] = val;
        else
          ((unsigned short*)Cv)[(long)blockIdx.z * batC + (row + rr) * ldc + col] = f2bf(val);
      }
    }
  }
}

__device__ __forceinline__ uint4 pack8(const float* x) {
  float4 a = *(const float4*)x;
  float4 b = *(const float4*)(x + 4);
  uint4 o;
  o.x = (unsigned int)f2bf(a.x) | ((unsigned int)f2bf(a.y) << 16);
  o.y = (unsigned int)f2bf(a.z) | ((unsigned int)f2bf(a.w) << 16);
  o.z = (unsigned int)f2bf(b.x) | ((unsigned int)f2bf(b.y) << 16);
  o.w = (unsigned int)f2bf(b.z) | ((unsigned int)f2bf(b.w) << 16);
  return o;
}

// pure fp32->bf16 convert of q/k/v. grid (512, 3), 16384 elems/block.
__global__ __launch_bounds__(256) void prep_qkv(
    const float* __restrict__ q, const float* __restrict__ k, const float* __restrict__ v,
    unsigned short* __restrict__ qb, unsigned short* __restrict__ kb,
    unsigned short* __restrict__ vb) {
  const float* X; unsigned short* Y;
  if (blockIdx.y == 0)      { X = q; Y = qb; }
  else if (blockIdx.y == 1) { X = k; Y = kb; }
  else                      { X = v; Y = vb; }
  const int tid = threadIdx.x;
  const long blk = (long)blockIdx.x * 16384;
#pragma unroll
  for (int it = 0; it < 8; ++it) {
    const long idx = blk + it * 2048 + tid * 8;
    *(uint4*)(Y + idx) = pack8(X + idx);
  }
}

// all weight converts in one dispatch. grid (512, 5):
//  y<4: big 1024x1024 matrices (Wq,Wk,Wv,Wo), x in [0,512)
//  y==4: six 16k matrices (QB,KB,VB,QA,KA,VA), x in [0,48): mat=x>>3, sub=x&7
__global__ __launch_bounds__(256) void cvt_all(
    const float* __restrict__ Wq, const float* __restrict__ Wk,
    const float* __restrict__ Wv, const float* __restrict__ Wo,
    const float* __restrict__ QB, const float* __restrict__ KB, const float* __restrict__ VB,
    const float* __restrict__ QA, const float* __restrict__ KA, const float* __restrict__ VA,
    unsigned short* __restrict__ wqb, unsigned short* __restrict__ wkb,
    unsigned short* __restrict__ wvb, unsigned short* __restrict__ wob,
    unsigned short* __restrict__ Bqb, unsigned short* __restrict__ Bkb, unsigned short* __restrict__ Bvb,
    unsigned short* __restrict__ Aqb, unsigned short* __restrict__ Akb, unsigned short* __restrict__ Avb) {
  if (blockIdx.y < 4) {
    const float* x; unsigned short* y;
    switch (blockIdx.y) {
      case 0: x = Wq; y = wqb; break;
      case 1: x = Wk; y = wkb; break;
      case 2: x = Wv; y = wvb; break;
      default: x = Wo; y = wob; break;
    }
    const long i = ((long)blockIdx.x * 256 + threadIdx.x) * 8;
    *(uint4*)(y + i) = pack8(x + i);
  } else {
    if (blockIdx.x >= 48) return;
    const int mat = blockIdx.x >> 3, sub = blockIdx.x & 7;
    const float* x; unsigned short* y;
    switch (mat) {
      case 0: x = QB; y = Bqb; break;
      case 1: x = KB; y = Bkb; break;
      case 2: x = VB; y = Bvb; break;
      case 3: x = QA; y = Aqb; break;
      case 4: x = KA; y = Akb; break;
      default: x = VA; y = Avb; break;
    }
    const long i = ((long)sub * 256 + threadIdx.x) * 8;
    *(uint4*)(y + i) = pack8(x + i);
  }
}

// T[8192][16] = Xb @ Am^T via MFMA. grid (128, 3): 64 rows/block, 16/wave.
__global__ __launch_bounds__(256) void lora_t_mfma(
    const unsigned short* __restrict__ qb, const unsigned short* __restrict__ kb,
    const unsigned short* __restrict__ vb,
    const unsigned short* __restrict__ Aq, const unsigned short* __restrict__ Ak,
    const unsigned short* __restrict__ Av,
    unsigned short* __restrict__ Tq, unsigned short* __restrict__ Tk,
    unsigned short* __restrict__ Tv) {
  const unsigned short* X; const unsigned short* Am; unsigned short* T;
  if (blockIdx.y == 0)      { X = qb; Am = Aq; T = Tq; }
  else if (blockIdx.y == 1) { X = kb; Am = Ak; T = Tk; }
  else                      { X = vb; Am = Av; T = Tv; }
  const int tid = threadIdx.x, wave = tid >> 6, lane = tid & 63;
  const int quad = lane >> 4, l16 = lane & 15;
  const long m0 = (long)blockIdx.x * 64 + wave * 16;
  floatx4 acc = (floatx4){0.f, 0.f, 0.f, 0.f};
  const unsigned short* xp = X + (m0 + l16) * 1024 + quad * 8;
  const unsigned short* ap = Am + (long)l16 * 1024 + quad * 8;
#pragma unroll 4
  for (int k0 = 0; k0 < 1024; k0 += 32) {
    short8 af = *(const short8*)(xp + k0);
    short8 bf = *(const short8*)(ap + k0);
    acc = __builtin_amdgcn_mfma_f32_16x16x32_bf16(af, bf, acc, 0, 0, 0);
  }
#pragma unroll
  for (int rr = 0; rr < 4; ++rr)
    T[(m0 + quad * 4 + rr) * 16 + l16] = f2bf(acc[rr]);
}

// in-place row softmax over 2048 bf16 scores; one block per row
__global__ __launch_bounds__(256) void softmax_kernel(unsigned short* __restrict__ S) {
  const long base = (long)blockIdx.x * 2048;
  const int tid = threadIdx.x;
  const int lane = tid & 63, wave = tid >> 6;
  __shared__ float redm[4], reds[4];
  uint4 raw = *(const uint4*)(S + base + tid * 8);
  unsigned int w[4] = {raw.x, raw.y, raw.z, raw.w};
  float v[8];
#pragma unroll
  for (int i = 0; i < 4; ++i) {
    v[2 * i]     = bf2f((unsigned short)(w[i] & 0xffffu));
    v[2 * i + 1] = bf2f((unsigned short)(w[i] >> 16));
  }
  float m = v[0];
#pragma unroll
  for (int i = 1; i < 8; ++i) m = fmaxf(m, v[i]);
  for (int off = 32; off >= 1; off >>= 1) m = fmaxf(m, __shfl_xor(m, off, 64));
  if (lane == 0) redm[wave] = m;
  __syncthreads();
  m = fmaxf(fmaxf(redm[0], redm[1]), fmaxf(redm[2], redm[3]));
  float e[8], s = 0.f;
#pragma unroll
  for (int i = 0; i < 8; ++i) { e[i] = __expf(v[i] - m); s += e[i]; }
  for (int off = 32; off >= 1; off >>= 1) s += __shfl_xor(s, off, 64);
  if (lane == 0) reds[wave] = s;
  __syncthreads();
  s = reds[0] + reds[1] + reds[2] + reds[3];
  const float inv = 1.0f / s;
  uint4 o;
  o.x = (unsigned int)f2bf(e[0] * inv) | ((unsigned int)f2bf(e[1] * inv) << 16);
  o.y = (unsigned int)f2bf(e[2] * inv) | ((unsigned int)f2bf(e[3] * inv) << 16);
  o.z = (unsigned int)f2bf(e[4] * inv) | ((unsigned int)f2bf(e[5] * inv) << 16);
  o.w = (unsigned int)f2bf(e[6] * inv) | ((unsigned int)f2bf(e[7] * inv) << 16);
  *(uint4*)(S + base + tid * 8) = o;
}

extern "C" void kernel_launch(void* const* d_in, const int* in_sizes, int n_in,
                              void* d_out, int out_size, void* d_ws, size_t ws_size,
                              hipStream_t stream) {
  const float* q  = (const float*)d_in[0];
  const float* k  = (const float*)d_in[1];
  const float* v  = (const float*)d_in[2];
  const float* Wq = (const float*)d_in[3];
  const float* Wk = (const float*)d_in[4];
  const float* Wv = (const float*)d_in[5];
  const float* QA = (const float*)d_in[6];
  const float* QB = (const float*)d_in[7];
  const float* KA = (const float*)d_in[8];
  const float* KB = (const float*)d_in[9];
  const float* VA = (const float*)d_in[10];
  const float* VB = (const float*)d_in[11];
  const float* Wo = (const float*)d_in[12];

  unsigned short* W = (unsigned short*)d_ws;
  const long SEe = (long)8192 * 1024;  // 8388608
  unsigned short* qb  = W;             // dead after Q-proj -> scores low half
  unsigned short* kb  = W + SEe;
  unsigned short* vb  = W + 2 * SEe;   // dead after V-proj -> attn buffer
  unsigned short* Qp  = W + 3 * SEe;
  unsigned short* Kp  = W + 4 * SEe;
  unsigned short* VT  = W + 5 * SEe;   // [1024][8192] = V^T
  unsigned short* wqb = W + 6 * SEe;
  unsigned short* wkb = wqb + 1048576;
  unsigned short* wvb = wkb + 1048576;
  unsigned short* wob = wvb + 1048576;
  unsigned short* Bqb = wob + 1048576;
  unsigned short* Bkb = Bqb + 16384;
  unsigned short* Bvb = Bkb + 16384;
  unsigned short* Aqb = Bvb + 16384;
  unsigned short* Akb = Aqb + 16384;
  unsigned short* Avb = Akb + 16384;
  unsigned short* Tq  = Avb + 16384;   // [8192][16]
  unsigned short* Tk  = Tq + 131072;
  unsigned short* Tv  = Tk + 131072;
  unsigned short* scores = W;          // [4][2048][2048] bf16, aliases qb+kb
  unsigned short* attn   = vb;         // [8192][1024] bf16, aliases vb

  dim3 blk(256, 1, 1);
  prep_qkv<<<dim3(512, 3, 1), blk, 0, stream>>>(q, k, v, qb, kb, vb);
  cvt_all<<<dim3(512, 5, 1), blk, 0, stream>>>(Wq, Wk, Wv, Wo, QB, KB, VB, QA, KA, VA,
                                               wqb, wkb, wvb, wob, Bqb, Bkb, Bvb, Aqb, Akb, Avb);
  lora_t_mfma<<<dim3(128, 3, 1), blk, 0, stream>>>(qb, kb, vb, Aqb, Akb, Avb, Tq, Tk, Tv);

  // Q = qb@Wq^T + Tq@Bq^T ; K likewise (z batches; M=8192,N=1024,K=1024)
  gemm_bt<true, false, true><<<dim3(8, 64, 2), blk, 0, stream>>>(
      qb, wqb, Qp, Tq, Bqb, 1024, 1024, 1024, 1024, 1.0f,
      SEe, 1048576, SEe, 131072, 16384);
  // VT = Wv@vb^T + Bv@Tv^T  (M=1024,N=8192): OWNN (partition wide N, stream 2MB A)
  gemm_bt<true, false, false><<<dim3(64, 8, 1), blk, 0, stream>>>(
      wvb, vb, VT, Bvb, Tv, 1024, 1024, 8192, 1024, 1.0f, 0, 0, 0, 0, 0);
  // scores = Qp@Kp^T / 32   (batched, M=N=2048,K=1024)
  gemm_bt<false, false, true><<<dim3(16, 16, 4), blk, 0, stream>>>(
      Qp, Kp, scores, nullptr, nullptr, 1024, 1024, 2048, 1024, 0.03125f,
      (long)S_LEN * E_DIM, (long)S_LEN * E_DIM, (long)S_LEN * S_LEN, 0, 0);
  softmax_kernel<<<8192, blk, 0, stream>>>(scores);
  // attn_out = P@V = P@(VT)^T  (batched, M=2048,N=1024,K=2048)
  gemm_bt<false, false, true><<<dim3(8, 16, 4), blk, 0, stream>>>(
      scores, VT, attn, nullptr, nullptr, 2048, 8192, 1024, 2048, 1.0f,
      (long)S_LEN * S_LEN, (long)S_LEN, (long)S_LEN * E_DIM, 0, 0);
  // final = attn@Wo^T -> fp32 d_out  (M=8192,N=1024,K=1024)
  gemm_bt<false, true, true><<<dim3(8, 64, 1), blk, 0, stream>>>(
      attn, wob, d_out, nullptr, nullptr, 1024, 1024, 1024, 1024, 1.0f, 0, 0, 0, 0, 0);
}